// Round 13
// baseline (14652.321 us; speedup 1.0000x reference)
//
#include <hip/hip_runtime.h>

// ---------------------------------------------------------------------------
// Persistent seq2seq LSTM, v13 = v12 + cached payload + per-XCD wb/inv.
// Root cause (R12 FETCH=9.5MB/step): UC payload stores bypass L2 AND LLC ->
// post-inv consumer reads miss to HBM (~900cy, 671GB/s) = the 17us/step
// plateau. v13: h-pack / conv_x / h0 / y0 use PLAIN CACHED stores (dirty in
// producer XCD L2). hwait is two-phase: leader polls 256 hflags ->
// fence(release,agent) = ONE buffer_wbl2/XCD/step (dirty payload -> LLC) ->
// wbdone[xcd] -> leaders poll 8 wbdone -> fence(acquire,agent) = ONE L2
// inv/XCD/step -> invdone -> non-leaders L1-inv only. Consumer refills now
// come from LLC, not HBM. y-pack / fp / out / flags stay UC (mid-step
// consumers, proven path). Everything else identical to v12.
// ---------------------------------------------------------------------------

#define TS 384

typedef __attribute__((ext_vector_type(8))) short bf16x8;
typedef __attribute__((ext_vector_type(4))) float f32x4;

// ws layout
#define WS_XR 4096u                      // x ring: 4 slots x (hi 128KB + lo 128KB)
#define XR_SLOT 262144u
#define WS_HP (WS_XR + 4u*XR_SLOT)       // h planes: 2 bufs x (hi 256KB + lo 256KB)
#define HP_BUF 524288u
#define WS_FPN (WS_HP + 2u*HP_BUF)       // fc partials 8*128*512*4 = 2MB
#define WS_TOTAL (WS_FPN + 2097152u)

#define MFMA __builtin_amdgcn_mfma_f32_16x16x32_bf16

__device__ __forceinline__ unsigned short bf16r(float v) {
  unsigned u = __float_as_uint(v);
  u += 0x7FFFu + ((u >> 16) & 1u);
  return (unsigned short)(u >> 16);
}
__device__ __forceinline__ float bf2f(unsigned short h) {
  return __uint_as_float(((unsigned)h) << 16);
}
__device__ __forceinline__ void split2(float v, short& hi, short& lo) {
  unsigned short h = bf16r(v);
  float r = v - bf2f(h);
  hi = (short)h; lo = (short)bf16r(r);
}
__device__ __forceinline__ float sigm(float v)  { return 1.0f / (1.0f + __expf(-v)); }
__device__ __forceinline__ float tanhfa(float v){ return 1.0f - 2.0f / (__expf(2.0f*v) + 1.0f); }

// UC (agent) helpers — used ONLY for flags / y-pack / fp / out
__device__ __forceinline__ void st_u64_uc(void* p, unsigned long long v) {
  __hip_atomic_store((unsigned long long*)p, v, __ATOMIC_RELAXED, __HIP_MEMORY_SCOPE_AGENT);
}
__device__ __forceinline__ unsigned long long ld_u64_uc(const void* p) {
  return __hip_atomic_load((const unsigned long long*)p, __ATOMIC_RELAXED, __HIP_MEMORY_SCOPE_AGENT);
}
__device__ __forceinline__ void st_u32_uc(unsigned* p, unsigned v) {
  __hip_atomic_store(p, v, __ATOMIC_RELAXED, __HIP_MEMORY_SCOPE_AGENT);
}
__device__ __forceinline__ unsigned ld_u32_uc(const unsigned* p) {
  return __hip_atomic_load(p, __ATOMIC_RELAXED, __HIP_MEMORY_SCOPE_AGENT);
}
__device__ __forceinline__ void st_f32_uc(float* p, float v) {
  __hip_atomic_store(p, v, __ATOMIC_RELAXED, __HIP_MEMORY_SCOPE_AGENT);
}
__device__ __forceinline__ float ld_f32_uc(const float* p) {
  return __hip_atomic_load(p, __ATOMIC_RELAXED, __HIP_MEMORY_SCOPE_AGENT);
}
// plain cached 64b store (payload path)
__device__ __forceinline__ void st_u64_c(void* p, unsigned long long v) {
  *(volatile unsigned long long*)p = v;
}

// ---- sync primitives --------------------------------------------------------
__device__ __forceinline__ void setflag(unsigned* flag, unsigned val) {
  asm volatile("s_waitcnt vmcnt(0)" ::: "memory");   // payload stores in L2
  __syncthreads();
  if (threadIdx.x == 0)
    __hip_atomic_store(flag, val, __ATOMIC_RELAXED, __HIP_MEMORY_SCOPE_AGENT);
}
// two-phase global h-wait:
// leader: poll 256 flags -> RELEASE (wb L2->LLC) -> wbdone[x] -> poll 8 wbdone
//         -> ACQUIRE (inv L2) -> invdone[x].
// non-leader: poll invdone[x] -> L1-only inv.
__device__ __forceinline__ void hwait(const unsigned* flags, unsigned* wbdone,
                                      unsigned* invdone_line, bool leader,
                                      unsigned target, int* sDead) {
  if (leader) {
    if (threadIdx.x < 64) {
      const unsigned long long* q = (const unsigned long long*)(flags + threadIdx.x * 4);
      unsigned spins = 0;
      for (;;) {
        unsigned long long q0 = ld_u64_uc(q), q1 = ld_u64_uc(q + 1);
        bool ok = ((unsigned)q0 >= target) && ((unsigned)(q0 >> 32) >= target)
               && ((unsigned)q1 >= target) && ((unsigned)(q1 >> 32) >= target);
        if (__all(ok)) break;
        if (++spins > (1u << 20)) { if (threadIdx.x == 0) *sDead = 1; break; }
      }
    }
    if (threadIdx.x == 0) {
      __builtin_amdgcn_fence(__ATOMIC_RELEASE, "agent");   // buffer_wbl2 (once/XCD)
      asm volatile("s_waitcnt vmcnt(0)" ::: "memory");
      st_u32_uc(wbdone + (int)( ((size_t)invdone_line >> 6) & 7 ), 0); // placeholder avoided below
    }
  }
  __syncthreads();
  (void)wbdone;
  (void)invdone_line;
  (void)sDead;
}

// NOTE: the real hwait is inlined in the kernel (needs xcd index); see below.

// ---- weight loaders --------------------------------------------------------
__device__ void load_gate_weights(const float* __restrict__ Wx, const float* __restrict__ Wh,
                                  int p, short* sBh, short* sBl) {
  for (int idx = threadIdx.x; idx < 24576; idx += 1024) {
    int j = idx & 7, l = (idx >> 3) & 63, kb = idx >> 9;
    int k = kb * 32 + ((l >> 4) << 3) + j;
    int c = l & 15;
    int gcol = (c >> 2) * 1024 + p * 4 + (c & 3);
    float wv = (k < 512) ? Wx[(size_t)k * 4096 + gcol]
                         : Wh[(size_t)(k - 512) * 4096 + gcol];
    short hi, lo; split2(wv, hi, lo);
    sBh[idx] = hi; sBl[idx] = lo;
  }
}
__device__ void load_fc_weights(const float* __restrict__ fcW, int kg, int cg,
                                short* sFh, short* sFl) {
  for (int idx = threadIdx.x; idx < 4096; idx += 1024) {
    int j = idx & 7, l = (idx >> 3) & 63, kb = idx >> 9;
    int unit = kg * 256 + kb * 32 + ((l >> 4) << 3) + j;
    int col = cg * 16 + (l & 15);
    short hi, lo; split2(fcW[(size_t)unit * 512 + col], hi, lo);
    sFh[idx] = hi; sFl[idx] = lo;
  }
}

// ---- gate GEMM -------------------------------------------------------------
template<int NKB, int D>
__device__ __forceinline__ void gg_pipe(const short* AH_, const short* AL_,
    const short* BH_, const short* BL_, int mt, int l,
    int kbA0, int kbB0, f32x4* acc)
{
  const bf16x8* AH = (const bf16x8*)AH_;
  const bf16x8* AL = (const bf16x8*)AL_;
  const bf16x8* BH = (const bf16x8*)BH_;
  const bf16x8* BL = (const bf16x8*)BL_;
  bf16x8 pah[D], pal[D];
  #pragma unroll
  for (int i = 0; i < D; ++i) {
    pah[i] = AH[((kbA0 + i) * 8 + mt) * 64 + l];
    pal[i] = AL[((kbA0 + i) * 8 + mt) * 64 + l];
  }
  #pragma unroll
  for (int i = 0; i < NKB; ++i) {
    bf16x8 ah = pah[i % D], al = pal[i % D];
    if (i + D < NKB) {
      pah[i % D] = AH[((kbA0 + i + D) * 8 + mt) * 64 + l];
      pal[i % D] = AL[((kbA0 + i + D) * 8 + mt) * 64 + l];
    }
    bf16x8 bh = BH[(kbB0 + i) * 64 + l];
    bf16x8 bl = BL[(kbB0 + i) * 64 + l];
    const int a = (i & 1) * 3;
    acc[a + 0] = MFMA(ah, bh, acc[a + 0], 0, 0, 0);
    acc[a + 1] = MFMA(ah, bl, acc[a + 1], 0, 0, 0);
    acc[a + 2] = MFMA(al, bh, acc[a + 2], 0, 0, 0);
  }
}
__device__ __forceinline__ void gg_finish(f32x4* acc, int kh, int mt, int l,
                                          float* LDSgate) {
  f32x4 s = (acc[0] + acc[3]) + ((acc[1] + acc[4]) + (acc[2] + acc[5]));
  const int col = l & 15, r0 = mt * 16 + ((l >> 4) << 2);
  float* plane = LDSgate + kh * 2176;
  #pragma unroll
  for (int j = 0; j < 4; ++j) plane[(r0 + j) * 17 + col] = s[j];
}

// ---- x conversion (CACHED stores now) --------------------------------------
__device__ __forceinline__ void conv_x(const float* __restrict__ xsrc,
                                       short* dstH, short* dstL, int p, int tl) {
  if (tl < 32) {
    int g = p * 32 + tl;
    int l = g & 63, mt = (g >> 6) & 7, kb = g >> 9;
    int row = mt * 16 + (l & 15), k = kb * 32 + ((l >> 4) << 3);
    const float* xs = xsrc + (size_t)row * 512 + k;
    unsigned long long h64[2] = {0, 0}, l64[2] = {0, 0};
    #pragma unroll
    for (int j = 0; j < 8; ++j) {
      short hi, lo; split2(xs[j], hi, lo);
      h64[j >> 2] |= (unsigned long long)(unsigned short)hi << ((j & 3) * 16);
      l64[j >> 2] |= (unsigned long long)(unsigned short)lo << ((j & 3) * 16);
    }
    int off = g * 8;
    st_u64_c(dstH + off, h64[0]); st_u64_c(dstH + off + 4, h64[1]);
    st_u64_c(dstL + off, l64[0]); st_u64_c(dstL + off + 4, l64[1]);
  }
}

__global__ void __launch_bounds__(1024, 1)
lstm13(const float* __restrict__ x, const float* __restrict__ h0p,
       const float* __restrict__ c0p, const float* __restrict__ eWx,
       const float* __restrict__ eWh, const float* __restrict__ eb,
       const float* __restrict__ dWx, const float* __restrict__ dWh,
       const float* __restrict__ db, const float* __restrict__ fcW,
       const float* __restrict__ fcb, float* __restrict__ out,
       char* __restrict__ ws)
{
  __shared__ __align__(16) short sBh[24576], sBl[24576];   // 96 KB
  __shared__ __align__(16) short sFh[4096], sFl[4096];     // 16 KB
  __shared__ float LDSgate[2 * 2176];                      // 17.4 KB
  __shared__ unsigned hsplit[512];
  __shared__ float ybuf[512];
  __shared__ float red[16];
  __shared__ int sDead, sLeader, sXcd;

  const int p = blockIdx.x, t = threadIdx.x;
  const int w = t >> 6, l = t & 63;
  const int mt = w & 7, kh = w >> 3;
  if (t == 0) sDead = 0;

  unsigned* hflag  = (unsigned*)ws;                 // 256 flags
  unsigned* yflag  = (unsigned*)(ws + 1024);        // 128 flags
  unsigned* fflag  = (unsigned*)(ws + 2048);        // 128 flags
  unsigned* elect  = (unsigned*)(ws + 3264);        // 8 counters
  unsigned* wbdone = (unsigned*)(ws + 3904);        // 8 epochs (one line)

  // ---- XCD id + one-time leader election ----
  if (t == 0) {
    unsigned xcd;
    asm volatile("s_getreg_b32 %0, hwreg(HW_REG_XCC_ID)" : "=s"(xcd));
    xcd &= 7u;
    sXcd = (int)xcd;
    unsigned old = __hip_atomic_fetch_add(&elect[xcd], 1u, __ATOMIC_ACQ_REL,
                                          __HIP_MEMORY_SCOPE_AGENT);
    sLeader = (old == 0u) ? 1 : 0;
  }
  __syncthreads();
  const bool leader = (sLeader != 0);
  const int myxcd = sXcd;
  unsigned* invd = (unsigned*)(ws + 3328 + myxcd * 64);

  // ---- inline two-phase hwait as a lambda ----
  auto HWAIT = [&](unsigned target) {
    if (leader) {
      if (t < 64) {
        const unsigned long long* q = (const unsigned long long*)(hflag + t * 4);
        unsigned spins = 0;
        for (;;) {
          unsigned long long q0 = ld_u64_uc(q), q1 = ld_u64_uc(q + 1);
          bool ok = ((unsigned)q0 >= target) && ((unsigned)(q0 >> 32) >= target)
                 && ((unsigned)q1 >= target) && ((unsigned)(q1 >> 32) >= target);
          if (__all(ok)) break;
          if (++spins > (1u << 20)) { if (t == 0) sDead = 1; break; }
        }
      }
      if (t == 0) {
        __builtin_amdgcn_fence(__ATOMIC_RELEASE, "agent");   // wb L2 -> LLC
        asm volatile("s_waitcnt vmcnt(0)" ::: "memory");
        st_u32_uc(&wbdone[myxcd], target);
        unsigned spins = 0;
        for (;;) {
          unsigned long long a = ld_u64_uc(wbdone), b = ld_u64_uc(wbdone + 2);
          unsigned long long c = ld_u64_uc(wbdone + 4), d = ld_u64_uc(wbdone + 6);
          bool ok = ((unsigned)a >= target) && ((unsigned)(a >> 32) >= target)
                 && ((unsigned)b >= target) && ((unsigned)(b >> 32) >= target)
                 && ((unsigned)c >= target) && ((unsigned)(c >> 32) >= target)
                 && ((unsigned)d >= target) && ((unsigned)(d >> 32) >= target);
          if (ok) break;
          if (++spins > (1u << 20)) { sDead = 1; break; }
        }
        __builtin_amdgcn_fence(__ATOMIC_ACQUIRE, "agent");   // inv L2 (once/XCD)
        st_u32_uc(invd, target);
        asm volatile("s_waitcnt vmcnt(0)" ::: "memory");
      }
    } else {
      if (t == 0) {
        unsigned spins = 0;
        while (ld_u32_uc(invd) < target) {
          if (++spins > (1u << 20)) { sDead = 1; break; }
        }
        asm volatile("buffer_inv sc0" ::: "memory");          // L1-only inv
        asm volatile("s_waitcnt vmcnt(0)" ::: "memory");
      }
    }
    __syncthreads();
  };
  auto WAIT128 = [&](const unsigned* flags, unsigned target) {
    if (t < 64) {
      const bool act = (t * 4) < 128;
      const unsigned long long* q = (const unsigned long long*)(flags + t * 4);
      unsigned spins = 0;
      for (;;) {
        bool ok = true;
        if (act) {
          unsigned long long q0 = ld_u64_uc(q), q1 = ld_u64_uc(q + 1);
          ok = ((unsigned)q0 >= target) && ((unsigned)(q0 >> 32) >= target)
            && ((unsigned)q1 >= target) && ((unsigned)(q1 >> 32) >= target);
        }
        if (__all(ok)) break;
        if (++spins > (1u << 20)) { if (t == 0) sDead = 1; break; }
      }
    }
    __syncthreads();
  };

  short* xrH[4]; short* xrL[4];
  #pragma unroll
  for (int s4 = 0; s4 < 4; ++s4) {
    xrH[s4] = (short*)(ws + WS_XR + s4 * XR_SLOT);
    xrL[s4] = (short*)(ws + WS_XR + s4 * XR_SLOT + 131072u);
  }
  short* hpH[2]; short* hpL[2];
  #pragma unroll
  for (int b2 = 0; b2 < 2; ++b2) {
    hpH[b2] = (short*)(ws + WS_HP + b2 * HP_BUF);
    hpL[b2] = (short*)(ws + WS_HP + b2 * HP_BUF + 262144u);
  }
  float* fp = (float*)(ws + WS_FPN);

  const int row_pw = t & 127, u_pw = (t >> 7) & 3;

  // ================= init =================
  load_gate_weights(eWx, eWh, p, sBh, sBl);
  conv_x(x, xrH[0], xrL[0], p, t);                       // x(0)
  conv_x(x + 65536, xrH[1], xrL[1], p, t);               // x(1)
  if (t < 64) {                                          // h0 -> hp[0] (cached)
    int hg = p * 64 + t;
    int ll = hg & 63, mtt = (hg >> 6) & 7, hk = hg >> 9;
    int row = mtt * 16 + (ll & 15), k = hk * 32 + ((ll >> 4) << 3);
    const float* hs = h0p + (size_t)row * 1024 + k;
    unsigned long long h64[2] = {0, 0}, l64[2] = {0, 0};
    #pragma unroll
    for (int j = 0; j < 8; ++j) {
      short hi, lo; split2(hs[j], hi, lo);
      h64[j >> 2] |= (unsigned long long)(unsigned short)hi << ((j & 3) * 16);
      l64[j >> 2] |= (unsigned long long)(unsigned short)lo << ((j & 3) * 16);
    }
    int off = hg * 8;
    st_u64_c(hpH[0] + off, h64[0]); st_u64_c(hpH[0] + off + 4, h64[1]);
    st_u64_c(hpL[0] + off, l64[0]); st_u64_c(hpL[0] + off + 4, l64[1]);
  }
  float creg = 0.f, bq0 = 0.f, bq1 = 0.f, bq2 = 0.f, bq3 = 0.f;
  if (t < 512) {
    creg = c0p[(size_t)row_pw * 1024 + p * 4 + u_pw];
    bq0 = eb[0 * 1024 + p * 4 + u_pw];
    bq1 = eb[1 * 1024 + p * 4 + u_pw];
    bq2 = eb[2 * 1024 + p * 4 + u_pw];
    bq3 = eb[3 * 1024 + p * 4 + u_pw];
  }
  setflag(&hflag[p], 1u);
  HWAIT(1u);                                             // init barrier (wb+inv)
  if (sDead) return;

  // ================= encoder =================
  for (int st = 0; st < TS; ++st) {
    int rb = st & 1, wb = rb ^ 1, xs = st & 3;
    f32x4 z = {0.f, 0.f, 0.f, 0.f};
    f32x4 acc[6] = {z, z, z, z, z, z};
    gg_pipe<8, 4>(xrH[xs], xrL[xs], sBh, sBl, mt, l, kh * 8, kh * 8, acc);
    HWAIT((unsigned)(st + 1));
    if (sDead) return;
    gg_pipe<16, 4>(hpH[rb], hpL[rb], sBh, sBl, mt, l, kh * 16, 16 + kh * 16, acc);
    gg_finish(acc, kh, mt, l, LDSgate);
    __syncthreads();
    if (t < 512) {
      float g0 = LDSgate[row_pw * 17 + 0  + u_pw] + LDSgate[2176 + row_pw * 17 + 0  + u_pw] + bq0;
      float g1 = LDSgate[row_pw * 17 + 4  + u_pw] + LDSgate[2176 + row_pw * 17 + 4  + u_pw] + bq1;
      float g2 = LDSgate[row_pw * 17 + 8  + u_pw] + LDSgate[2176 + row_pw * 17 + 8  + u_pw] + bq2;
      float g3 = LDSgate[row_pw * 17 + 12 + u_pw] + LDSgate[2176 + row_pw * 17 + 12 + u_pw] + bq3;
      creg = sigm(g1) * creg + sigm(g0) * tanhfa(g2);
      float h = sigm(g3) * tanhfa(creg);
      short hi, lo; split2(h, hi, lo);
      hsplit[u_pw * 128 + row_pw] = ((unsigned)(unsigned short)hi << 16) | (unsigned short)lo;
    } else if (st + 2 < TS) {
      conv_x(x + (size_t)(st + 2) * 65536, xrH[(st + 2) & 3], xrL[(st + 2) & 3], p, t - 512);
    }
    __syncthreads();
    if (t < 128) {                                       // pack h (cached)
      int r = t;
      unsigned w0 = hsplit[r], w1 = hsplit[128 + r], w2 = hsplit[256 + r], w3 = hsplit[384 + r];
      unsigned long long hi64 = (unsigned long long)(w0 >> 16)
        | ((unsigned long long)(w1 >> 16) << 16)
        | ((unsigned long long)(w2 >> 16) << 32)
        | ((unsigned long long)(w3 >> 16) << 48);
      unsigned long long lo64 = (unsigned long long)(w0 & 0xFFFFu)
        | ((unsigned long long)(w1 & 0xFFFFu) << 16)
        | ((unsigned long long)(w2 & 0xFFFFu) << 32)
        | ((unsigned long long)(w3 & 0xFFFFu) << 48);
      int hk = p >> 3, mtt = r >> 4;
      int lane_ = (((p >> 1) & 3) << 4) | (r & 15);
      int off = ((hk * 8 + mtt) * 64 + lane_) * 8 + (p & 1) * 4;
      st_u64_c(hpH[wb] + off, hi64);
      st_u64_c(hpL[wb] + off, lo64);
    }
    setflag(&hflag[p], (unsigned)(st + 2));
  }

  // ================= switch to decoder =================
  load_gate_weights(dWx, dWh, p, sBh, sBl);
  if (p >= 128) load_fc_weights(fcW, (p - 128) >> 5, (p - 128) & 31, sFh, sFl);
  if (t < 32) {                                          // zero y0 (cached)
    int off = (p * 32 + t) * 8;
    st_u64_c(xrH[0] + off, 0ull); st_u64_c(xrH[0] + off + 4, 0ull);
    st_u64_c(xrL[0] + off, 0ull); st_u64_c(xrL[0] + off + 4, 0ull);
  }
  creg = 0.0f;
  if (t < 512) {
    bq0 = db[0 * 1024 + p * 4 + u_pw];
    bq1 = db[1 * 1024 + p * 4 + u_pw];
    bq2 = db[2 * 1024 + p * 4 + u_pw];
    bq3 = db[3 * 1024 + p * 4 + u_pw];
  }
  float fcb_r = (t < 512) ? fcb[t] : 0.f;
  setflag(&hflag[p], (unsigned)(TS + 2));

  // ================= decoder =================
  const unsigned DB = (unsigned)(TS + 2);
  for (int st = 0; st < TS; ++st) {
    const int rb = st & 1, wb = rb ^ 1;
    f32x4 z = {0.f, 0.f, 0.f, 0.f};
    f32x4 acc[6] = {z, z, z, z, z, z};
    HWAIT(DB + (unsigned)st);
    if (sDead) return;
    if (p >= 128) {
      const int f = p - 128, kg = f >> 5, cg = f & 31;
      if (st >= 1) {                                     // fc(h(st-1)), cached
        const bf16x8* AH = (const bf16x8*)hpH[rb];
        const bf16x8* AL = (const bf16x8*)hpL[rb];
        const bf16x8* FB = (const bf16x8*)sFh;
        const bf16x8* FL = (const bf16x8*)sFl;
        f32x4 a0 = z, a1 = z, a2 = z;
        #pragma unroll
        for (int kb = 0; kb < 4; ++kb) {
          int gkb = kg * 8 + kh * 4 + kb;
          bf16x8 ah = AH[(gkb * 8 + mt) * 64 + l];
          bf16x8 al = AL[(gkb * 8 + mt) * 64 + l];
          bf16x8 bh = FB[(kh * 4 + kb) * 64 + l];
          bf16x8 bl = FL[(kh * 4 + kb) * 64 + l];
          a0 = MFMA(ah, bh, a0, 0, 0, 0);
          a1 = MFMA(ah, bl, a1, 0, 0, 0);
          a2 = MFMA(al, bh, a2, 0, 0, 0);
        }
        f32x4 s = a0 + (a1 + a2);
        int slice = kg * 2 + kh;
        int col = cg * 16 + (l & 15), r0 = mt * 16 + ((l >> 4) << 2);
        #pragma unroll
        for (int j = 0; j < 4; ++j)
          st_f32_uc(&fp[(size_t)(slice * 128 + r0 + j) * 512 + col], s[j]);
        setflag(&fflag[f], (unsigned)st);
      }
      gg_pipe<16, 4>(hpH[rb], hpL[rb], sBh, sBl, mt, l, kh * 16, 16 + kh * 16, acc);
      if (st >= 1) { WAIT128(yflag, (unsigned)st); if (sDead) return; }
      gg_pipe<8, 4>(xrH[rb], xrL[rb], sBh, sBl, mt, l, kh * 8, kh * 8, acc);
    } else {
      gg_pipe<16, 4>(hpH[rb], hpL[rb], sBh, sBl, mt, l, kh * 16, 16 + kh * 16, acc);
      if (st >= 1) {
        WAIT128(fflag, (unsigned)st);
        if (sDead) return;
        float v = 0.f, e = 0.f, mx;
        if (t < 512) {
          float tv[8];
          #pragma unroll
          for (int s8 = 0; s8 < 8; ++s8)
            tv[s8] = ld_f32_uc(&fp[(size_t)(s8 * 128 + p) * 512 + t]);
          v = fcb_r + ((tv[0] + tv[1]) + (tv[2] + tv[3]))
                    + ((tv[4] + tv[5]) + (tv[6] + tv[7]));
          mx = v;
          #pragma unroll
          for (int o = 32; o > 0; o >>= 1) mx = fmaxf(mx, __shfl_xor(mx, o));
          if (l == 0) red[w] = mx;
        }
        __syncthreads();
        if (t < 512) {
          mx = red[0];
          #pragma unroll
          for (int i = 1; i < 8; ++i) mx = fmaxf(mx, red[i]);
          e = __expf(v - mx);
          float ss = e;
          #pragma unroll
          for (int o = 32; o > 0; o >>= 1) ss += __shfl_xor(ss, o);
          if (l == 0) red[8 + w] = ss;
        }
        __syncthreads();
        if (t < 512) {
          float ss = (red[8] + red[9]) + (red[10] + red[11])
                   + (red[12] + red[13]) + (red[14] + red[15]);
          float y = e / ss;
          st_f32_uc(&out[((size_t)(st - 1) * 128 + p) * 512 + t], y);
          ybuf[t] = y;
        }
        __syncthreads();
        if (t < 64) {                                    // pack y(st-1) UC (mid-step consumer)
          int kb = t >> 2, seg = t & 3;
          int k = kb * 32 + seg * 8;
          int lane_ = (seg << 4) | (p & 15), mtt = p >> 4;
          int off = ((kb * 8 + mtt) * 64 + lane_) * 8;
          unsigned long long h64[2] = {0, 0}, l64[2] = {0, 0};
          #pragma unroll
          for (int j = 0; j < 8; ++j) {
            short hi, lo; split2(ybuf[k + j], hi, lo);
            h64[j >> 2] |= (unsigned long long)(unsigned short)hi << ((j & 3) * 16);
            l64[j >> 2] |= (unsigned long long)(unsigned short)lo << ((j & 3) * 16);
          }
          st_u64_uc(xrH[rb] + off, h64[0]); st_u64_uc(xrH[rb] + off + 4, h64[1]);
          st_u64_uc(xrL[rb] + off, l64[0]); st_u64_uc(xrL[rb] + off + 4, l64[1]);
        }
        setflag(&yflag[p], (unsigned)st);
        WAIT128(yflag, (unsigned)st);
        if (sDead) return;
      }
      gg_pipe<8, 4>(xrH[rb], xrL[rb], sBh, sBl, mt, l, kh * 8, kh * 8, acc);
    }
    gg_finish(acc, kh, mt, l, LDSgate);
    __syncthreads();
    if (t < 512) {
      float g0 = LDSgate[row_pw * 17 + 0  + u_pw] + LDSgate[2176 + row_pw * 17 + 0  + u_pw] + bq0;
      float g1 = LDSgate[row_pw * 17 + 4  + u_pw] + LDSgate[2176 + row_pw * 17 + 4  + u_pw] + bq1;
      float g2 = LDSgate[row_pw * 17 + 8  + u_pw] + LDSgate[2176 + row_pw * 17 + 8  + u_pw] + bq2;
      float g3 = LDSgate[row_pw * 17 + 12 + u_pw] + LDSgate[2176 + row_pw * 17 + 12 + u_pw] + bq3;
      creg = sigm(g1) * creg + sigm(g0) * tanhfa(g2);
      float h = sigm(g3) * tanhfa(creg);
      short hi, lo; split2(h, hi, lo);
      hsplit[u_pw * 128 + row_pw] = ((unsigned)(unsigned short)hi << 16) | (unsigned short)lo;
    }
    __syncthreads();
    if (t < 128) {                                       // pack h (cached)
      int r = t;
      unsigned w0 = hsplit[r], w1 = hsplit[128 + r], w2 = hsplit[256 + r], w3 = hsplit[384 + r];
      unsigned long long hi64 = (unsigned long long)(w0 >> 16)
        | ((unsigned long long)(w1 >> 16) << 16)
        | ((unsigned long long)(w2 >> 16) << 32)
        | ((unsigned long long)(w3 >> 16) << 48);
      unsigned long long lo64 = (unsigned long long)(w0 & 0xFFFFu)
        | ((unsigned long long)(w1 & 0xFFFFu) << 16)
        | ((unsigned long long)(w2 & 0xFFFFu) << 32)
        | ((unsigned long long)(w3 & 0xFFFFu) << 48);
      int hk = p >> 3, mtt = r >> 4;
      int lane_ = (((p >> 1) & 3) << 4) | (r & 15);
      int off = ((hk * 8 + mtt) * 64 + lane_) * 8 + (p & 1) * 4;
      st_u64_c(hpH[wb] + off, hi64);
      st_u64_c(hpL[wb] + off, lo64);
    }
    setflag(&hflag[p], DB + (unsigned)(st + 1));
  }

  // ================= epilogue: fc+softmax for step TS-1 =================
  {
    const int rb = TS & 1;
    HWAIT(DB + (unsigned)TS);
    if (sDead) return;
    if (p >= 128) {
      const int f = p - 128, kg = f >> 5, cg = f & 31;
      const bf16x8* AH = (const bf16x8*)hpH[rb];
      const bf16x8* AL = (const bf16x8*)hpL[rb];
      const bf16x8* FB = (const bf16x8*)sFh;
      const bf16x8* FL = (const bf16x8*)sFl;
      f32x4 z = {0.f, 0.f, 0.f, 0.f};
      f32x4 a0 = z, a1 = z, a2 = z;
      #pragma unroll
      for (int kb = 0; kb < 4; ++kb) {
        int gkb = kg * 8 + kh * 4 + kb;
        bf16x8 ah = AH[(gkb * 8 + mt) * 64 + l];
        bf16x8 al = AL[(gkb * 8 + mt) * 64 + l];
        bf16x8 bh = FB[(kh * 4 + kb) * 64 + l];
        bf16x8 bl = FL[(kh * 4 + kb) * 64 + l];
        a0 = MFMA(ah, bh, a0, 0, 0, 0);
        a1 = MFMA(ah, bl, a1, 0, 0, 0);
        a2 = MFMA(al, bh, a2, 0, 0, 0);
      }
      f32x4 s = a0 + (a1 + a2);
      int slice = kg * 2 + kh;
      int col = cg * 16 + (l & 15), r0 = mt * 16 + ((l >> 4) << 2);
      #pragma unroll
      for (int j = 0; j < 4; ++j)
        st_f32_uc(&fp[(size_t)(slice * 128 + r0 + j) * 512 + col], s[j]);
      setflag(&fflag[p - 128], (unsigned)TS);
    } else {
      WAIT128(fflag, (unsigned)TS);
      if (sDead) return;
      float v = 0.f, e = 0.f, mx;
      if (t < 512) {
        float tv[8];
        #pragma unroll
        for (int s8 = 0; s8 < 8; ++s8)
          tv[s8] = ld_f32_uc(&fp[(size_t)(s8 * 128 + p) * 512 + t]);
        v = fcb_r + ((tv[0] + tv[1]) + (tv[2] + tv[3]))
                  + ((tv[4] + tv[5]) + (tv[6] + tv[7]));
        mx = v;
        #pragma unroll
        for (int o = 32; o > 0; o >>= 1) mx = fmaxf(mx, __shfl_xor(mx, o));
        if (l == 0) red[w] = mx;
      }
      __syncthreads();
      if (t < 512) {
        mx = red[0];
        #pragma unroll
        for (int i = 1; i < 8; ++i) mx = fmaxf(mx, red[i]);
        e = __expf(v - mx);
        float ss = e;
        #pragma unroll
        for (int o = 32; o > 0; o >>= 1) ss += __shfl_xor(ss, o);
        if (l == 0) red[8 + w] = ss;
      }
      __syncthreads();
      if (t < 512) {
        float ss = (red[8] + red[9]) + (red[10] + red[11])
                 + (red[12] + red[13]) + (red[14] + red[15]);
        st_f32_uc(&out[((size_t)(TS - 1) * 128 + p) * 512 + t], e / ss);
      }
    }
  }
}

extern "C" void kernel_launch(void* const* d_in, const int* in_sizes, int n_in,
                              void* d_out, int out_size, void* d_ws, size_t ws_size,
                              hipStream_t stream) {
  const float* x   = (const float*)d_in[0];
  const float* h0  = (const float*)d_in[1];
  const float* c0  = (const float*)d_in[2];
  const float* eWx = (const float*)d_in[3];
  const float* eWh = (const float*)d_in[4];
  const float* eb  = (const float*)d_in[5];
  const float* dWx = (const float*)d_in[6];
  const float* dWh = (const float*)d_in[7];
  const float* db  = (const float*)d_in[8];
  const float* fcW = (const float*)d_in[9];
  const float* fcb = (const float*)d_in[10];
  float* out = (float*)d_out;

  if (ws_size < (size_t)WS_TOTAL) {
    hipMemsetAsync(d_out, 0xFF, (size_t)out_size * sizeof(float), stream);
    return;
  }
  hipMemsetAsync(d_ws, 0, 4096, stream);   // flags + elect + wbdone + invdone
  hipLaunchKernelGGL(lstm13, dim3(256), dim3(1024), 0, stream,
                     x, h0, c0, eWx, eWh, eb, dWx, dWh, db, fcW, fcb, out,
                     (char*)d_ws);
}